// Round 3
// baseline (144.746 us; speedup 1.0000x reference)
//
#include <hip/hip_runtime.h>
#include <math.h>

// Distral per-task MLP: 32769 heads, h = relu(W1[3->100] x + b1),
// p = softmax(W2[100->5] h + b2).  ~3.6 KB read/head, ~119 MB total.
//
// R11: dense global access via LDS staging.
// R10 falsified wave-level MLP as the bottleneck: with a data-dependence
// asm fence forcing all 17 loads in flight (~150 KB/CU outstanding),
// time was unchanged (~40 us, 2.9 TB/s delivered).  Remaining
// difference vs the 6.5 TB/s fill/copy kernels: per-INSTRUCTION address
// density.  Our gathers (lane c at stride 48B) touch ~38 cache lines
// per VMEM instruction; ~650 line-requests/wave at the observed 1
// wave/1524cy = ~0.42 req/cy/CU -- an L1/TA request-rate ceiling, not a
// byte ceiling.  Fills/copies issue 1 dense span per instruction.
// Fix: per block of 8 heads, stage W1/b1/W2 slices (contiguous,
// 16B-aligned in global) into LDS with global_load_lds width=16 -- 30
// instructions, each a dense contiguous 1KB transfer (uniform LDS dest
// + lane*16, per-lane global src; clamp src to array end for tail
// blocks -- clamped lanes only feed invalid heads).  Compute gathers
// fragments from LDS where strided reads are cheap.  x and b2 (5
// floats, not clamp-safe to 16B) stay as direct register loads issued
// before the barrier.  Head->block map and compute math = R8/R10.
// Gates: LDS_Block_Size=30720 proves structure; if time stays ~40us,
// density theory is falsified -> system ceiling.

#define N_HEADS 32769
#define HID     100
#define OUT     5
#define PART    4100             // heads per XCD partition (8*4100 >= N_HEADS)
#define BLK_PER_PART 513         // ceil(4100/8 heads-per-block)

__global__ __launch_bounds__(256) void distral_kernel(
    const float* __restrict__ x,
    const float* __restrict__ W1,
    const float* __restrict__ b1,
    const float* __restrict__ W2,
    const float* __restrict__ b2,
    float* __restrict__ out)
{
    // LDS image of this block's 8 heads:
    //   [0    .. 2560) W1 slice  (8*300 f, padded to 10 KiB region)
    //   [2560 .. 3584) b1 slice  (8*100 f, padded to 4 KiB region)
    //   [3584 .. 7680) W2 slice  (8*500 f, padded to 16 KiB region)
    __shared__ __align__(16) float lds[7680];   // 30 KiB -> 5 blocks/CU

    const int tid  = threadIdx.x;
    const int lane = tid & 63;
    const int wv   = tid >> 6;
    const int half = lane >> 5;          // 0/1: head owned by this 32-lane half
    const int ll   = lane & 31;

    // XCD swizzle: partition p = bid & 7; contiguous ~15 MB window per XCD.
    const int p  = blockIdx.x & 7;
    const int i  = blockIdx.x >> 3;              // 0..BLK_PER_PART-1
    const int H0 = p * PART + i * 8;             // first head of this block

    const size_t W1len = (size_t)N_HEADS * 300;
    const size_t b1len = (size_t)N_HEADS * 100;
    const size_t W2len = (size_t)N_HEADS * 500;

    // ---- STAGE: 30 dense 1KB global->LDS DMAs, interleaved across waves ----
#pragma unroll
    for (int j = 0; j < 8; ++j) {
        const int k = j * 4 + wv;                // wave-uniform instr id
        if (k < 30) {
            const float* base;
            size_t srcf, len;
            int dst;
            if (k < 10) {        // W1 region
                base = W1; srcf = (size_t)H0 * 300 + (size_t)k * 256;
                dst  = k * 256;              len = W1len;
            } else if (k < 14) { // b1 region
                base = b1; srcf = (size_t)H0 * 100 + (size_t)(k - 10) * 256;
                dst  = 2560 + (k - 10) * 256; len = b1len;
            } else {             // W2 region
                base = W2; srcf = (size_t)H0 * 500 + (size_t)(k - 14) * 256;
                dst  = 3584 + (k - 14) * 256; len = W2len;
            }
            size_t sf = srcf + (size_t)(lane * 4);
            const size_t lim = len - 4;          // len % 4 == 0 for W1/b1/W2
            if (sf > lim) sf = lim;              // clamp: only affects invalid heads
            __builtin_amdgcn_global_load_lds(
                (const __attribute__((address_space(1))) unsigned int*)(base + sf),
                (__attribute__((address_space(3))) unsigned int*)(&lds[dst]),
                16, 0, 0);
        }
    }

    const int hl   = wv * 2 + half;              // head-local 0..7
    const int slot = i * 8 + hl;
    const int hraw = H0 + hl;
    const bool valid = (slot < PART) && (hraw < N_HEADS);
    const int  head  = valid ? hraw : (N_HEADS - 1);

    // ---- direct small loads (latency hides under DMA drain + barrier) ----
    const float x0 = x[head * 3 + 0];
    const float x1 = x[head * 3 + 1];
    const float x2 = x[head * 3 + 2];
    float b2v[OUT];
#pragma unroll
    for (int o = 0; o < OUT; ++o) b2v[o] = b2[(size_t)head * OUT + o];

    __syncthreads();   // compiler emits s_waitcnt vmcnt(0) drain before barrier

    // ---- compute from LDS (strided gathers are cheap here) ----
    const int c = (ll < 25) ? ll : 24;
    const bool active = (ll < 25);

    const float4* W1v = (const float4*)&lds[hl * 300 + 12 * c];
    const float4 q0 = W1v[0];
    const float4 q1 = W1v[1];
    const float4 q2 = W1v[2];
    const float4 bq = *(const float4*)&lds[2560 + hl * 100 + 4 * c];
    float4 w2r[OUT];
#pragma unroll
    for (int o = 0; o < OUT; ++o)
        w2r[o] = *(const float4*)&lds[3584 + hl * 500 + 100 * o + 4 * c];

    // layer 1: this lane's 4 hidden units
    const float h0 = fmaxf(fmaf(q0.x, x0, fmaf(q0.y, x1, fmaf(q0.z, x2, bq.x))), 0.f);
    const float h1 = fmaxf(fmaf(q0.w, x0, fmaf(q1.x, x1, fmaf(q1.y, x2, bq.y))), 0.f);
    const float h2 = fmaxf(fmaf(q1.z, x0, fmaf(q1.w, x1, fmaf(q2.x, x2, bq.z))), 0.f);
    const float h3 = fmaxf(fmaf(q2.y, x0, fmaf(q2.z, x1, fmaf(q2.w, x2, bq.w))), 0.f);

    // layer 2: per-lane dot4 + 32-half butterfly
    float logit[OUT];
#pragma unroll
    for (int o = 0; o < OUT; ++o) {
        float pt = fmaf(h0, w2r[o].x, fmaf(h1, w2r[o].y,
                   fmaf(h2, w2r[o].z, h3 * w2r[o].w)));
        pt = active ? pt : 0.0f;
#pragma unroll
        for (int m = 16; m > 0; m >>= 1)
            pt += __shfl_xor(pt, m, 64); // masks <32: stays within the half
        logit[o] = pt + b2v[o];
    }

    // softmax (uniform within each half)
    float mx = -INFINITY;
#pragma unroll
    for (int o = 0; o < OUT; ++o) mx = fmaxf(mx, logit[o]);
    float e[OUT], s = 0.0f;
#pragma unroll
    for (int o = 0; o < OUT; ++o) { e[o] = __expf(logit[o] - mx); s += e[o]; }
    const float inv = 1.0f / s;

    if (valid && ll < OUT) {
        float v = (ll == 0) ? e[0]
                : (ll == 1) ? e[1]
                : (ll == 2) ? e[2]
                : (ll == 3) ? e[3]
                :             e[4];
        out[(size_t)head * OUT + ll] = v * inv;
    }
}

extern "C" void kernel_launch(void* const* d_in, const int* in_sizes, int n_in,
                              void* d_out, int out_size, void* d_ws, size_t ws_size,
                              hipStream_t stream) {
    const float* x  = (const float*)d_in[0];
    const float* W1 = (const float*)d_in[1];
    const float* b1 = (const float*)d_in[2];
    const float* W2 = (const float*)d_in[3];
    const float* b2 = (const float*)d_in[4];
    float* out = (float*)d_out;

    distral_kernel<<<8 * BLK_PER_PART, 256, 0, stream>>>(x, W1, b1, W2, b2, out);
}

// Round 4
// 141.991 us; speedup vs baseline: 1.0194x; 1.0194x over previous
//
#include <hip/hip_runtime.h>
#include <math.h>

// Distral per-task MLP: 32769 heads, h = relu(W1[3->100] x + b1),
// p = softmax(W2[100->5] h + b2).  ~3.6 KB read/head, ~119 MB total.
//
// R12: non-temporal weight loads to bypass the L3 mixed-miss gate.
// R0/R10/R11 (gather / register+fence / dense LDS-DMA) are all
// 40.70+-0.02 us with FETCH_SIZE pinned at 58.2 MB: duration is
// structure- and occupancy-independent, equal to FETCH / 1.43 TB/s.
// Diagnosis: harness poison-fills evict ~half the 119 MB working set
// from Infinity Cache at LINE granularity, so the HBM miss stream is a
// random sprinkle of 64-128B lines regardless of request density --
// row-activation-bound DRAM at ~18% efficiency.  Request-side structure
// can't fix a miss-pattern problem.  Fix: read W1/b1/W2 with nt
// (non-temporal) so nothing allocates in L2/L3 -> every iteration
// streams all 119 MB from HBM as dense sequential bursts.
// Gates: FETCH_SIZE ~119 MB proves nt reached cache policy; dur then
// tells us the dense-read rate.  If FETCH jumps but dur doesn't drop,
// mixed-L3 state was net-positive -> revert + ceiling.
// Compute structure = R10 (register float4, asm MLP fence, lane owns
// hidden chunk 4c, two heads per wave in 32-lane halves, XCD-
// partitioned head order).

#define N_HEADS 32769
#define HID     100
#define OUT     5
#define CHUNKS  25               // float4 chunks per head
#define PART    4100             // heads per XCD partition (8*4100 >= N_HEADS)
#define BLK_PER_PART 513         // ceil(4100/8 heads-per-block)

typedef float f32x4 __attribute__((ext_vector_type(4)));

__device__ __forceinline__ f32x4 nt4(const f32x4* p) {
    return __builtin_nontemporal_load(p);
}

__global__ __launch_bounds__(256) void distral_kernel(
    const float* __restrict__ x,
    const float* __restrict__ W1,
    const float* __restrict__ b1,
    const float* __restrict__ W2,
    const float* __restrict__ b2,
    float* __restrict__ out)
{
    const int lane = threadIdx.x & 63;
    const int half = lane >> 5;          // 0/1: which head this half-wave owns
    const int ll   = lane & 31;
    const int wv   = threadIdx.x >> 6;

    // XCD swizzle: partition p = bid & 7 lands round-robin on XCD p,
    // and reads only heads [p*PART, p*PART+4100) -- contiguous ~15 MB.
    const int p    = blockIdx.x & 7;
    const int i    = blockIdx.x >> 3;            // 0..BLK_PER_PART-1
    const int slot = i * 8 + wv * 2 + half;      // head index within partition
    const int hraw = p * PART + slot;
    const bool valid = (slot < PART) && (hraw < N_HEADS);
    const int  head  = valid ? hraw : (N_HEADS - 1);   // clamp keeps loads legal

    const int c = (ll < CHUNKS) ? ll : (CHUNKS - 1);
    const bool active = (ll < CHUNKS);

    const f32x4* W1q = (const f32x4*)(W1 + (size_t)head * 300);  // 16B-aligned
    const f32x4* b1q = (const f32x4*)(b1 + (size_t)head * 100);
    const f32x4* W2q = (const f32x4*)(W2 + (size_t)head * 500);

    // ---- LOAD PHASE: all independent, all non-temporal ----
    f32x4 q0  = nt4(&W1q[3 * c + 0]);    // W1 rows 4c..4c+3 (12 floats)
    f32x4 q1  = nt4(&W1q[3 * c + 1]);
    f32x4 q2  = nt4(&W1q[3 * c + 2]);
    f32x4 bq  = nt4(&b1q[c]);
    f32x4 w20 = nt4(&W2q[CHUNKS * 0 + c]);   // W2[o][4c..4c+3]
    f32x4 w21 = nt4(&W2q[CHUNKS * 1 + c]);
    f32x4 w22 = nt4(&W2q[CHUNKS * 2 + c]);
    f32x4 w23 = nt4(&W2q[CHUNKS * 3 + c]);
    f32x4 w24 = nt4(&W2q[CHUNKS * 4 + c]);

    float x0 = x[head * 3 + 0];
    float x1 = x[head * 3 + 1];
    float x2 = x[head * 3 + 2];

    // b2 row: 5 floats, dword-aligned.  16B load + 1 dword (tiny; keep
    // cached -- 0.66 MB total, not worth nt).
    f32x4 b2a;
    __builtin_memcpy(&b2a, b2 + (size_t)head * OUT, sizeof(f32x4));
    float b2e = b2[(size_t)head * OUT + 4];

    // Fence: reads every load result -> all loads issue before this
    // point, one batched waitcnt (R10-verified mechanism).
    asm volatile("" :
        "+v"(q0), "+v"(q1), "+v"(q2), "+v"(bq),
        "+v"(w20), "+v"(w21), "+v"(w22), "+v"(w23), "+v"(w24),
        "+v"(x0), "+v"(x1), "+v"(x2), "+v"(b2a), "+v"(b2e));

    // ---- layer 1: this lane's 4 hidden units, in-lane ----
    const float h0 = fmaxf(fmaf(q0[0], x0, fmaf(q0[1], x1, fmaf(q0[2], x2, bq[0]))), 0.f);
    const float h1 = fmaxf(fmaf(q0[3], x0, fmaf(q1[0], x1, fmaf(q1[1], x2, bq[1]))), 0.f);
    const float h2 = fmaxf(fmaf(q1[2], x0, fmaf(q1[3], x1, fmaf(q2[0], x2, bq[2]))), 0.f);
    const float h3 = fmaxf(fmaf(q2[1], x0, fmaf(q2[2], x1, fmaf(q2[3], x2, bq[3]))), 0.f);

    // ---- layer 2: per-lane dot4 + 32-half butterfly ----
    const f32x4 w2arr[OUT] = { w20, w21, w22, w23, w24 };
    const float b2v[OUT]   = { b2a[0], b2a[1], b2a[2], b2a[3], b2e };

    float logit[OUT];
#pragma unroll
    for (int o = 0; o < OUT; ++o) {
        float pt = fmaf(h0, w2arr[o][0], fmaf(h1, w2arr[o][1],
                   fmaf(h2, w2arr[o][2], h3 * w2arr[o][3])));
        pt = active ? pt : 0.0f;
#pragma unroll
        for (int m = 16; m > 0; m >>= 1)
            pt += __shfl_xor(pt, m, 64); // masks <32: stays within the half
        logit[o] = pt + b2v[o];
    }

    // ---- softmax (uniform within each half) ----
    float mx = -INFINITY;
#pragma unroll
    for (int o = 0; o < OUT; ++o) mx = fmaxf(mx, logit[o]);
    float e[OUT], s = 0.0f;
#pragma unroll
    for (int o = 0; o < OUT; ++o) { e[o] = __expf(logit[o] - mx); s += e[o]; }
    const float inv = 1.0f / s;

    if (valid && ll < OUT) {
        float v = (ll == 0) ? e[0]
                : (ll == 1) ? e[1]
                : (ll == 2) ? e[2]
                : (ll == 3) ? e[3]
                :             e[4];
        out[(size_t)head * OUT + ll] = v * inv;
    }
}

extern "C" void kernel_launch(void* const* d_in, const int* in_sizes, int n_in,
                              void* d_out, int out_size, void* d_ws, size_t ws_size,
                              hipStream_t stream) {
    const float* x  = (const float*)d_in[0];
    const float* W1 = (const float*)d_in[1];
    const float* b1 = (const float*)d_in[2];
    const float* W2 = (const float*)d_in[3];
    const float* b2 = (const float*)d_in[4];
    float* out = (float*)d_out;

    distral_kernel<<<8 * BLK_PER_PART, 256, 0, stream>>>(x, W1, b1, W2, b2, out);
}